// Round 10
// baseline (63.341 us; speedup 1.0000x reference)
//
#include <hip/hip_runtime.h>
#include <cstddef>

constexpr int B_  = 16;
constexpr int K_  = 5;
constexpr int C_  = 256;
constexpr int HW_ = 128 * 128;
constexpr int Q_  = 64;
constexpr float T_ = 0.2f;
constexpr int WPS_ = HW_ / 4;   // packed words per sample = 4096
constexpr int PB_  = 16;        // pred blocks per sample (4096/256)

typedef float f4 __attribute__((ext_vector_type(4)));

// ---------------------------------------------------------------------------
// Kernel 1: per-pixel prediction (byte-packed, 4 px/uint) + per-block counts.
// (byte-identical to round 4/8 — known good)
// ---------------------------------------------------------------------------
__global__ __launch_bounds__(256) void pred_kernel(
    const float* __restrict__ res1, const int* __restrict__ gt,
    const int* __restrict__ label_bs, unsigned int* __restrict__ predp,
    int* __restrict__ counts_blk, int* __restrict__ flag)
{
    if (blockIdx.x == 0 && threadIdx.x == 0) *flag = 0;

    int idx = blockIdx.x * 256 + threadIdx.x;   // word index, 0 .. B*HW/4-1
    int b  = idx >> 12;                         // 4096 words per sample
    int p4 = idx & 4095;
    int lb = label_bs[0];
    int k0, k1, k2, k3;
    if (b < lb) {
        int4 g = reinterpret_cast<const int4*>(gt + (size_t)b * HW_)[p4];
        k0 = g.x; k1 = g.y; k2 = g.z; k3 = g.w;
    } else {
        const f4* r = reinterpret_cast<const f4*>(res1 + (size_t)b * K_ * HW_) + p4;
        f4 best = __builtin_nontemporal_load(r);
        k0 = k1 = k2 = k3 = 0;
        #pragma unroll
        for (int k = 1; k < K_; ++k) {
            f4 v = __builtin_nontemporal_load(r + (size_t)k * WPS_);
            if (v.x > best.x) { best.x = v.x; k0 = k; }   // strict >: first max
            if (v.y > best.y) { best.y = v.y; k1 = k; }
            if (v.z > best.z) { best.z = v.z; k2 = k; }
            if (v.w > best.w) { best.w = v.w; k3 = k; }
        }
    }
    predp[idx] = (unsigned)(k0 & 0xFF) | ((unsigned)(k1 & 0xFF) << 8)
               | ((unsigned)(k2 & 0xFF) << 16) | ((unsigned)(k3 & 0xFF) << 24);

    int cnt[K_];
    #pragma unroll
    for (int k = 0; k < K_; ++k)
        cnt[k] = (k0 == k) + (k1 == k) + (k2 == k) + (k3 == k);

    int lane = threadIdx.x & 63, wv = threadIdx.x >> 6;
    __shared__ int redc[4][K_];
    #pragma unroll
    for (int k = 0; k < K_; ++k) {
        int v = cnt[k];
        #pragma unroll
        for (int off = 32; off > 0; off >>= 1) v += __shfl_down(v, off);
        if (lane == 0) redc[wv][k] = v;
    }
    __syncthreads();
    if (threadIdx.x < K_)
        counts_blk[blockIdx.x * K_ + threadIdx.x] =
            redc[0][threadIdx.x] + redc[1][threadIdx.x] +
            redc[2][threadIdx.x] + redc[3][threadIdx.x];
}

// ---------------------------------------------------------------------------
// Kernel 2: masked segment sums, 2 channel rows per block (same sample).
// One unpack + one set of 0/1 masks per packed word is shared by both rows'
// FMAs: VALU per row-word drops ~64 -> ~42, flipping the kernel from
// VALU-bound (observed ~5.2 TB/s) to BW-bound. Load pattern per stream is
// unchanged (NT f4, sequential). 2048 uniform blocks = 8/CU.
// ---------------------------------------------------------------------------
__global__ __launch_bounds__(256) void segsum_kernel(
    const float* __restrict__ fea, const unsigned int* __restrict__ predp,
    float* __restrict__ sums)
{
    int bc = blockIdx.x;          // 0..2047
    int b  = bc >> 7;             // sample
    int c0 = bc & 127;            // rows c0 and c0+128
    int tid = threadIdx.x;
    const f4* frow0 = reinterpret_cast<const f4*>(fea + ((size_t)b * C_ + c0) * HW_);
    const f4* frow1 = reinterpret_cast<const f4*>(fea + ((size_t)b * C_ + c0 + 128) * HW_);
    const unsigned int* prow = predp + (size_t)b * WPS_;

    float acc0[K_] = {}, acc1[K_] = {};
    #pragma unroll 2
    for (int i = tid; i < WPS_; i += 256) {
        f4 v0 = __builtin_nontemporal_load(frow0 + i);
        f4 v1 = __builtin_nontemporal_load(frow1 + i);
        unsigned u = prow[i];
        int k0 = u & 255, k1 = (u >> 8) & 255, k2 = (u >> 16) & 255, k3 = u >> 24;
        #pragma unroll
        for (int k = 0; k < K_; ++k) {
            float m0 = (k0 == k) ? 1.f : 0.f;   // masks shared by both rows
            float m1 = (k1 == k) ? 1.f : 0.f;
            float m2 = (k2 == k) ? 1.f : 0.f;
            float m3 = (k3 == k) ? 1.f : 0.f;
            acc0[k] += ((m0 * v0.x + m1 * v0.y) + (m2 * v0.z + m3 * v0.w));
            acc1[k] += ((m0 * v1.x + m1 * v1.y) + (m2 * v1.z + m3 * v1.w));
        }
    }

    __shared__ float red[4][2 * K_];
    int lane = tid & 63, wv = tid >> 6;
    #pragma unroll
    for (int k = 0; k < K_; ++k) {
        float v = acc0[k];
        #pragma unroll
        for (int off = 32; off > 0; off >>= 1) v += __shfl_down(v, off);
        if (lane == 0) red[wv][k] = v;
        float w = acc1[k];
        #pragma unroll
        for (int off = 32; off > 0; off >>= 1) w += __shfl_down(w, off);
        if (lane == 0) red[wv][K_ + k] = w;
    }
    __syncthreads();
    if (tid < K_) {
        sums[((size_t)b * K_ + tid) * C_ + c0] =
            red[0][tid] + red[1][tid] + red[2][tid] + red[3][tid];
        sums[((size_t)b * K_ + tid) * C_ + c0 + 128] =
            red[0][K_ + tid] + red[1][K_ + tid] + red[2][K_ + tid] + red[3][K_ + tid];
    }
}

// ---------------------------------------------------------------------------
// Kernel 3: contrastive tail, one block per (b,k), 320 threads = 5 waves:
// wave j computes the single j-dot (serial-chain form the compiler pipelines
// well). Last block folds in the valid/denom masking + final reductions.
// (byte-identical to round 8 — known good)
// ---------------------------------------------------------------------------
__global__ __launch_bounds__(320) void loss_kernel(
    const float* __restrict__ sums, const int* __restrict__ counts_blk,
    const float* __restrict__ queues, float* __restrict__ logprob,
    int* __restrict__ counts_g, int* __restrict__ flag, float* __restrict__ out)
{
    int bk = blockIdx.x;
    int b = bk / K_;
    int k = bk - b * K_;
    int tid = threadIdx.x, lane = tid & 63, wv = tid >> 6;   // wv in 0..4

    __shared__ float key[C_];
    __shared__ float wred[5];
    __shared__ float sumE_s[K_];
    __shared__ float lpos_s[Q_];
    __shared__ int   cnt_s[K_];
    __shared__ int   last_s;

    // per-sample class counts: sum the 16 per-block vectors
    if (tid < K_) {
        int s = 0;
        #pragma unroll
        for (int blk = 0; blk < PB_; ++blk)
            s += counts_blk[(b * PB_ + blk) * K_ + tid];
        cnt_s[tid] = s;
        if (k == 0) counts_g[b * K_ + tid] = s;   // for the final reduction
    }
    __syncthreads();

    // prev (faithful cummax off-by-one): last present class with index < k
    int prev = -1;
    #pragma unroll
    for (int j = 0; j < K_; ++j)
        if (j < k && cnt_s[j] > 0) prev = j;
    int pk = prev < 0 ? 0 : prev;   // query = keys[max(prev,0)]

    // mean of class pk, L2-normalized over C (threads 0..255 own channels;
    // wave 4 contributes zero to the norm)
    float m = (tid < C_)
        ? sums[((size_t)b * K_ + pk) * C_ + tid] / fmaxf((float)cnt_s[pk], 1.0f)
        : 0.f;
    float s = m * m;
    #pragma unroll
    for (int off = 32; off > 0; off >>= 1) s += __shfl_down(s, off);
    if (lane == 0) wred[wv] = s;
    __syncthreads();
    float nrm = sqrtf(wred[0] + wred[1] + wred[2] + wred[3] + wred[4]);
    if (tid < C_) key[tid] = m / fmaxf(nrm, 1e-12f);
    __syncthreads();

    // sim[k,j,:]: wave wv owns exactly j = wv; lanes = q. Serial-chain dot
    // (compiler software-pipelines the independent loads).
    {
        int j = wv;   // 0..4 == K_ waves, one dot each
        const float* qj = queues + (size_t)j * C_ * Q_ + lane;
        float acc = 0.f;
        for (int c = 0; c < C_; ++c)
            acc += key[c] * qj[(size_t)c * Q_];
        acc = acc / T_;
        float e = expf(acc);
        float se = e;
        #pragma unroll
        for (int off = 32; off > 0; off >>= 1) se += __shfl_down(se, off);
        if (lane == 0) sumE_s[j] = se;
        if (j == k) lpos_s[lane] = acc;
    }
    __syncthreads();

    if (wv == 0) {
        float neg = 0.f;
        #pragma unroll
        for (int j = 0; j < K_; ++j)
            if (j != k) neg += sumE_s[j];
        float lp = lpos_s[lane];
        float term = lp - logf(expf(lp) + neg);
        #pragma unroll
        for (int off = 32; off > 0; off >>= 1) term += __shfl_down(term, off);
        if (lane == 0) logprob[bk] = term * (1.0f / (float)Q_);
    }
    __syncthreads();

    // last-block final reduction
    if (tid == 0) {
        __threadfence();
        last_s = (atomicAdd(flag, 1) == B_ * K_ - 1);
    }
    __syncthreads();
    if (last_s && wv == 0) {
        __threadfence();
        float per = 0.f;
        if (lane < B_) {
            int last = -1, smallest = -1, npres = 0;
            float lsum = 0.f;
            #pragma unroll
            for (int kk = 0; kk < K_; ++kk) {
                bool pres = counts_g[lane * K_ + kk] > 0;
                bool valid = pres && smallest >= 0 && last >= 0;
                if (valid) lsum += -logprob[lane * K_ + kk];
                if (pres && smallest < 0) smallest = kk;
                if (pres) { ++npres; last = kk; }
            }
            int denom = npres - 1;
            per = (denom > 0) ? (lsum / (float)denom) : 0.f;
        }
        #pragma unroll
        for (int off = 32; off > 0; off >>= 1) per += __shfl_down(per, off);
        if (lane == 0) out[0] = per / (float)B_;
    }
}

// ---------------------------------------------------------------------------
extern "C" void kernel_launch(void* const* d_in, const int* in_sizes, int n_in,
                              void* d_out, int out_size, void* d_ws, size_t ws_size,
                              hipStream_t stream)
{
    const float* res1     = (const float*)d_in[0];
    const float* fea1     = (const float*)d_in[1];
    const float* queues   = (const float*)d_in[2];
    const int*   gt       = (const int*)d_in[3];
    const int*   label_bs = (const int*)d_in[4];
    float* out = (float*)d_out;

    char* ws = (char*)d_ws;
    unsigned int* predp = (unsigned int*)ws;                        // 256 KB
    float* sums       = (float*)(ws + (size_t)B_ * WPS_ * 4);       // B*K*C floats
    int*   counts_blk = (int*)(sums + (size_t)B_ * K_ * C_);        // 256*K ints
    int*   counts_g   = counts_blk + B_ * PB_ * K_;                 // B*K ints
    int*   flag       = counts_g + B_ * K_;                         // 1 int
    float* logprob    = (float*)(flag + 1);                         // B*K floats

    pred_kernel<<<B_ * WPS_ / 256, 256, 0, stream>>>(res1, gt, label_bs, predp,
                                                     counts_blk, flag);
    segsum_kernel<<<B_ * C_ / 2, 256, 0, stream>>>(fea1, predp, sums);
    loss_kernel<<<B_ * K_, 320, 0, stream>>>(sums, counts_blk, queues, logprob,
                                             counts_g, flag, out);
}

// Round 11
// 62.492 us; speedup vs baseline: 1.0136x; 1.0136x over previous
//
#include <hip/hip_runtime.h>
#include <cstddef>

constexpr int B_  = 16;
constexpr int K_  = 5;
constexpr int C_  = 256;
constexpr int HW_ = 128 * 128;
constexpr int Q_  = 64;
constexpr float T_ = 0.2f;
constexpr int WPS_ = HW_ / 4;   // packed words per sample = 4096
constexpr int PB_  = 16;        // pred blocks per sample (4096/256)

typedef float f4 __attribute__((ext_vector_type(4)));

// ---------------------------------------------------------------------------
// Kernel 1: per-pixel prediction (byte-packed, 4 px/uint) + per-block counts.
// (byte-identical to round 4/8 — known good)
// ---------------------------------------------------------------------------
__global__ __launch_bounds__(256) void pred_kernel(
    const float* __restrict__ res1, const int* __restrict__ gt,
    const int* __restrict__ label_bs, unsigned int* __restrict__ predp,
    int* __restrict__ counts_blk, int* __restrict__ flag)
{
    if (blockIdx.x == 0 && threadIdx.x == 0) *flag = 0;

    int idx = blockIdx.x * 256 + threadIdx.x;   // word index, 0 .. B*HW/4-1
    int b  = idx >> 12;                         // 4096 words per sample
    int p4 = idx & 4095;
    int lb = label_bs[0];
    int k0, k1, k2, k3;
    if (b < lb) {
        int4 g = reinterpret_cast<const int4*>(gt + (size_t)b * HW_)[p4];
        k0 = g.x; k1 = g.y; k2 = g.z; k3 = g.w;
    } else {
        const f4* r = reinterpret_cast<const f4*>(res1 + (size_t)b * K_ * HW_) + p4;
        f4 best = __builtin_nontemporal_load(r);
        k0 = k1 = k2 = k3 = 0;
        #pragma unroll
        for (int k = 1; k < K_; ++k) {
            f4 v = __builtin_nontemporal_load(r + (size_t)k * WPS_);
            if (v.x > best.x) { best.x = v.x; k0 = k; }   // strict >: first max
            if (v.y > best.y) { best.y = v.y; k1 = k; }
            if (v.z > best.z) { best.z = v.z; k2 = k; }
            if (v.w > best.w) { best.w = v.w; k3 = k; }
        }
    }
    predp[idx] = (unsigned)(k0 & 0xFF) | ((unsigned)(k1 & 0xFF) << 8)
               | ((unsigned)(k2 & 0xFF) << 16) | ((unsigned)(k3 & 0xFF) << 24);

    int cnt[K_];
    #pragma unroll
    for (int k = 0; k < K_; ++k)
        cnt[k] = (k0 == k) + (k1 == k) + (k2 == k) + (k3 == k);

    int lane = threadIdx.x & 63, wv = threadIdx.x >> 6;
    __shared__ int redc[4][K_];
    #pragma unroll
    for (int k = 0; k < K_; ++k) {
        int v = cnt[k];
        #pragma unroll
        for (int off = 32; off > 0; off >>= 1) v += __shfl_down(v, off);
        if (lane == 0) redc[wv][k] = v;
    }
    __syncthreads();
    if (threadIdx.x < K_)
        counts_blk[blockIdx.x * K_ + threadIdx.x] =
            redc[0][threadIdx.x] + redc[1][threadIdx.x] +
            redc[2][threadIdx.x] + redc[3][threadIdx.x];
}

// ---------------------------------------------------------------------------
// Kernel 2: masked segment sums. One block per (b,c) row (4096 blocks);
// NT float4 streaming + byte-packed preds; unique-owner direct writes.
// Single variable vs R8: unroll 4 -> 8 (doubles loads in flight per thread;
// ~70 VGPR keeps ~8 waves/SIMD).
// ---------------------------------------------------------------------------
__global__ __launch_bounds__(256) void segsum_kernel(
    const float* __restrict__ fea, const unsigned int* __restrict__ predp,
    float* __restrict__ sums)
{
    int bc = blockIdx.x;
    int b = bc >> 8;              // / C_
    int c = bc & (C_ - 1);
    int tid = threadIdx.x;
    const f4* frow = reinterpret_cast<const f4*>(fea + ((size_t)b * C_ + c) * HW_);
    const unsigned int* prow = predp + (size_t)b * WPS_;

    float acc[K_] = {};
    #pragma unroll 8
    for (int i = tid; i < WPS_; i += 256) {
        f4 v = __builtin_nontemporal_load(frow + i);
        unsigned u = prow[i];
        int k0 = u & 255, k1 = (u >> 8) & 255, k2 = (u >> 16) & 255, k3 = u >> 24;
        #pragma unroll
        for (int k = 0; k < K_; ++k) {
            acc[k] += (k0 == k ? v.x : 0.f)
                    + (k1 == k ? v.y : 0.f)
                    + (k2 == k ? v.z : 0.f)
                    + (k3 == k ? v.w : 0.f);
        }
    }

    __shared__ float red[4][K_];
    int lane = tid & 63, wv = tid >> 6;
    #pragma unroll
    for (int k = 0; k < K_; ++k) {
        float v = acc[k];
        #pragma unroll
        for (int off = 32; off > 0; off >>= 1) v += __shfl_down(v, off);
        if (lane == 0) red[wv][k] = v;
    }
    __syncthreads();
    if (tid < K_)
        sums[((size_t)b * K_ + tid) * C_ + c] =
            red[0][tid] + red[1][tid] + red[2][tid] + red[3][tid];
}

// ---------------------------------------------------------------------------
// Kernel 3: contrastive tail, one block per (b,k), 320 threads = 5 waves:
// wave j computes the single j-dot (serial-chain form the compiler pipelines
// well). Last block folds in the valid/denom masking + final reductions.
// (byte-identical to round 8 — known good)
// ---------------------------------------------------------------------------
__global__ __launch_bounds__(320) void loss_kernel(
    const float* __restrict__ sums, const int* __restrict__ counts_blk,
    const float* __restrict__ queues, float* __restrict__ logprob,
    int* __restrict__ counts_g, int* __restrict__ flag, float* __restrict__ out)
{
    int bk = blockIdx.x;
    int b = bk / K_;
    int k = bk - b * K_;
    int tid = threadIdx.x, lane = tid & 63, wv = tid >> 6;   // wv in 0..4

    __shared__ float key[C_];
    __shared__ float wred[5];
    __shared__ float sumE_s[K_];
    __shared__ float lpos_s[Q_];
    __shared__ int   cnt_s[K_];
    __shared__ int   last_s;

    // per-sample class counts: sum the 16 per-block vectors
    if (tid < K_) {
        int s = 0;
        #pragma unroll
        for (int blk = 0; blk < PB_; ++blk)
            s += counts_blk[(b * PB_ + blk) * K_ + tid];
        cnt_s[tid] = s;
        if (k == 0) counts_g[b * K_ + tid] = s;   // for the final reduction
    }
    __syncthreads();

    // prev (faithful cummax off-by-one): last present class with index < k
    int prev = -1;
    #pragma unroll
    for (int j = 0; j < K_; ++j)
        if (j < k && cnt_s[j] > 0) prev = j;
    int pk = prev < 0 ? 0 : prev;   // query = keys[max(prev,0)]

    // mean of class pk, L2-normalized over C (threads 0..255 own channels;
    // wave 4 contributes zero to the norm)
    float m = (tid < C_)
        ? sums[((size_t)b * K_ + pk) * C_ + tid] / fmaxf((float)cnt_s[pk], 1.0f)
        : 0.f;
    float s = m * m;
    #pragma unroll
    for (int off = 32; off > 0; off >>= 1) s += __shfl_down(s, off);
    if (lane == 0) wred[wv] = s;
    __syncthreads();
    float nrm = sqrtf(wred[0] + wred[1] + wred[2] + wred[3] + wred[4]);
    if (tid < C_) key[tid] = m / fmaxf(nrm, 1e-12f);
    __syncthreads();

    // sim[k,j,:]: wave wv owns exactly j = wv; lanes = q. Serial-chain dot
    // (compiler software-pipelines the independent loads).
    {
        int j = wv;   // 0..4 == K_ waves, one dot each
        const float* qj = queues + (size_t)j * C_ * Q_ + lane;
        float acc = 0.f;
        for (int c = 0; c < C_; ++c)
            acc += key[c] * qj[(size_t)c * Q_];
        acc = acc / T_;
        float e = expf(acc);
        float se = e;
        #pragma unroll
        for (int off = 32; off > 0; off >>= 1) se += __shfl_down(se, off);
        if (lane == 0) sumE_s[j] = se;
        if (j == k) lpos_s[lane] = acc;
    }
    __syncthreads();

    if (wv == 0) {
        float neg = 0.f;
        #pragma unroll
        for (int j = 0; j < K_; ++j)
            if (j != k) neg += sumE_s[j];
        float lp = lpos_s[lane];
        float term = lp - logf(expf(lp) + neg);
        #pragma unroll
        for (int off = 32; off > 0; off >>= 1) term += __shfl_down(term, off);
        if (lane == 0) logprob[bk] = term * (1.0f / (float)Q_);
    }
    __syncthreads();

    // last-block final reduction
    if (tid == 0) {
        __threadfence();
        last_s = (atomicAdd(flag, 1) == B_ * K_ - 1);
    }
    __syncthreads();
    if (last_s && wv == 0) {
        __threadfence();
        float per = 0.f;
        if (lane < B_) {
            int last = -1, smallest = -1, npres = 0;
            float lsum = 0.f;
            #pragma unroll
            for (int kk = 0; kk < K_; ++kk) {
                bool pres = counts_g[lane * K_ + kk] > 0;
                bool valid = pres && smallest >= 0 && last >= 0;
                if (valid) lsum += -logprob[lane * K_ + kk];
                if (pres && smallest < 0) smallest = kk;
                if (pres) { ++npres; last = kk; }
            }
            int denom = npres - 1;
            per = (denom > 0) ? (lsum / (float)denom) : 0.f;
        }
        #pragma unroll
        for (int off = 32; off > 0; off >>= 1) per += __shfl_down(per, off);
        if (lane == 0) out[0] = per / (float)B_;
    }
}

// ---------------------------------------------------------------------------
extern "C" void kernel_launch(void* const* d_in, const int* in_sizes, int n_in,
                              void* d_out, int out_size, void* d_ws, size_t ws_size,
                              hipStream_t stream)
{
    const float* res1     = (const float*)d_in[0];
    const float* fea1     = (const float*)d_in[1];
    const float* queues   = (const float*)d_in[2];
    const int*   gt       = (const int*)d_in[3];
    const int*   label_bs = (const int*)d_in[4];
    float* out = (float*)d_out;

    char* ws = (char*)d_ws;
    unsigned int* predp = (unsigned int*)ws;                        // 256 KB
    float* sums       = (float*)(ws + (size_t)B_ * WPS_ * 4);       // B*K*C floats
    int*   counts_blk = (int*)(sums + (size_t)B_ * K_ * C_);        // 256*K ints
    int*   counts_g   = counts_blk + B_ * PB_ * K_;                 // B*K ints
    int*   flag       = counts_g + B_ * K_;                         // 1 int
    float* logprob    = (float*)(flag + 1);                         // B*K floats

    pred_kernel<<<B_ * WPS_ / 256, 256, 0, stream>>>(res1, gt, label_bs, predp,
                                                     counts_blk, flag);
    segsum_kernel<<<B_ * C_, 256, 0, stream>>>(fea1, predp, sums);
    loss_kernel<<<B_ * K_, 320, 0, stream>>>(sums, counts_blk, queues, logprob,
                                             counts_g, flag, out);
}